// Round 7
// baseline (123.271 us; speedup 1.0000x reference)
//
#include <hip/hip_runtime.h>
#include <cstddef>

// Problem constants
#define B_DIM 64
#define C_DIM 256
#define T_DIM 120
#define V_DIM 25
#define TV    3000                      // T_DIM * V_DIM
#define CTILE 16
#define NROWS (B_DIM * C_DIM)           // 16384 rows of TV floats
#define ROWF4 (TV / 4)                  // 750 float4 per row

// add_kernel geometry: ATOTAL (f4 stride between batch elements) is an exact
// multiple of ROWF4, so each thread's within-row offset (t0, r, selects) is
// computed once. BATCH independent loads issued per loop body.
#define ABLOCKS 1500
#define ATHREADS 256
#define ATOTAL (ABLOCKS * ATHREADS)     // 384000 f4 = 750 * 512 rows
#define AROWSTEP (ATOTAL / ROWF4)       // 512 rows per batch element
#define BATCH 8
#define SUPERS (NROWS / (AROWSTEP * BATCH))  // 4 exactly, zero remainder

typedef float f4v __attribute__((ext_vector_type(4)));

// ---------------------------------------------------------------------------
// Kernel A: fold the two linear layers.
//   WcT[i][c] = sum_j Wo[c][j] * Wv[j][i]
//   bc[c]     = sum_i Wo[c][i] * bv[i] + bo[c]
// ---------------------------------------------------------------------------
__global__ __launch_bounds__(256) void make_wc(
    const float* __restrict__ Wo, const float* __restrict__ Wv,
    const float* __restrict__ bv, const float* __restrict__ bo,
    float* __restrict__ WcT, float* __restrict__ bc) {
  const int c = blockIdx.x;
  const int i = threadIdx.x;

  float acc = 0.0f;
#pragma unroll 8
  for (int j = 0; j < C_DIM; ++j) {
    acc = fmaf(Wo[c * C_DIM + j], Wv[j * C_DIM + i], acc);
  }
  WcT[i * C_DIM + c] = acc;

  __shared__ float red[C_DIM];
  red[i] = Wo[c * C_DIM + i] * bv[i];
  __syncthreads();
  for (int s = 128; s > 0; s >>= 1) {
    if (i < s) red[i] += red[i + s];
    __syncthreads();
  }
  if (i == 0) bc[c] = red[0] + bo[c];
}

// ---------------------------------------------------------------------------
// Kernel B: ov[b*C + c][t] = bc[c] + sum_i WcT[i][c] * y[b][i][t]
// grid = (B, C/CTILE), block = 256. y loads double-buffered; WcT wave-uniform.
// ---------------------------------------------------------------------------
__global__ __launch_bounds__(256) void ov_kernel(
    const float* __restrict__ y, const float* __restrict__ WcT,
    const float* __restrict__ bc, float* __restrict__ ov) {
  const int b   = blockIdx.x;
  const int c0  = blockIdx.y * CTILE;
  const int tid = threadIdx.x;
  const int chalf = tid >> 7;      // wave-uniform
  const int t     = tid & 127;
  if (t >= T_DIM) return;

  const int cb = __builtin_amdgcn_readfirstlane(c0 + chalf * 8);

  float acc[8];
#pragma unroll
  for (int cl = 0; cl < 8; ++cl) acc[cl] = bc[cb + cl];

  const float* yb = y + (size_t)b * C_DIM * T_DIM + t;

  float yv[8];
#pragma unroll
  for (int u = 0; u < 8; ++u) yv[u] = yb[(size_t)u * T_DIM];

#define FMA_GROUP(ibase)                                              \
  _Pragma("unroll")                                                   \
  for (int u = 0; u < 8; ++u) {                                       \
    const f4v* wr = (const f4v*)(WcT + ((ibase) + u) * C_DIM + cb);   \
    const f4v w0 = wr[0];                                             \
    const f4v w1 = wr[1];                                             \
    acc[0] = fmaf(w0.x, yv[u], acc[0]);                               \
    acc[1] = fmaf(w0.y, yv[u], acc[1]);                               \
    acc[2] = fmaf(w0.z, yv[u], acc[2]);                               \
    acc[3] = fmaf(w0.w, yv[u], acc[3]);                               \
    acc[4] = fmaf(w1.x, yv[u], acc[4]);                               \
    acc[5] = fmaf(w1.y, yv[u], acc[5]);                               \
    acc[6] = fmaf(w1.z, yv[u], acc[6]);                               \
    acc[7] = fmaf(w1.w, yv[u], acc[7]);                               \
  }

  for (int i = 0; i < C_DIM - 8; i += 8) {
    float yn[8];
#pragma unroll
    for (int u = 0; u < 8; ++u) yn[u] = yb[(size_t)(i + 8 + u) * T_DIM];
    FMA_GROUP(i)
#pragma unroll
    for (int u = 0; u < 8; ++u) yv[u] = yn[u];
  }
  FMA_GROUP(C_DIM - 8)
#undef FMA_GROUP

  float* ovp = ov + ((size_t)b * C_DIM + cb) * T_DIM + t;
#pragma unroll
  for (int cl = 0; cl < 8; ++cl) ovp[(size_t)cl * T_DIM] = acc[cl];
}

// ---------------------------------------------------------------------------
// Kernel C: streaming z = x + ov[row][t0].
// A/B vs R6: ONLY change is nontemporal store -> plain store. R3/R5/R6 all
// pinned at ~113 us with nt stores (WRITE 192 MB / 113 us = 1.7 TB/s cap);
// fillBuffer does 7 TB/s with plain stores.
// ---------------------------------------------------------------------------
__global__ __launch_bounds__(ATHREADS) void add_kernel(
    const float* __restrict__ x, const float* __restrict__ ov,
    float* __restrict__ z) {
  const int gtid = blockIdx.x * ATHREADS + threadIdx.x;  // [0, ATOTAL)
  const int row0 = gtid / ROWF4;                         // [0, AROWSTEP)
  const int w4   = gtid - row0 * ROWF4;                  // [0, 750)
  const int pos  = w4 * 4;
  const int t0   = pos / V_DIM;
  const int r    = pos - t0 * V_DIM;                     // 0..24

  // component j uses next t's addend iff r + j >= 25; crossing implies
  // pos+3 < 3000 so t0+1 <= 119 (in bounds). If no cross, o1 = t0 (safe).
  const bool s1 = (r + 1 >= V_DIM), s2 = (r + 2 >= V_DIM), s3 = (r + 3 >= V_DIM);
  const int  o1 = t0 + (s3 ? 1 : 0);

  const f4v* __restrict__ xin  = (const f4v*)x;
  f4v* __restrict__       zout = (f4v*)z;

  size_t idx = (size_t)gtid;
  const float* ovp = ov + (size_t)row0 * T_DIM;

  for (int s = 0; s < SUPERS; ++s) {
    f4v   xv[BATCH];
    float a0[BATCH], a1[BATCH];

#pragma unroll
    for (int j = 0; j < BATCH; ++j)
      xv[j] = xin[idx + (size_t)j * ATOTAL];

#pragma unroll
    for (int j = 0; j < BATCH; ++j) {
      const float* o = ovp + (size_t)j * AROWSTEP * T_DIM;
      a0[j] = o[t0];
      a1[j] = o[o1];
    }

#pragma unroll
    for (int j = 0; j < BATCH; ++j) {
      f4v o;
      o.x = xv[j].x + a0[j];
      o.y = xv[j].y + (s1 ? a1[j] : a0[j]);
      o.z = xv[j].z + (s2 ? a1[j] : a0[j]);
      o.w = xv[j].w + (s3 ? a1[j] : a0[j]);
      zout[idx + (size_t)j * ATOTAL] = o;
    }

    idx += (size_t)BATCH * ATOTAL;
    ovp += (size_t)BATCH * AROWSTEP * T_DIM;
  }
}

// ---------------------------------------------------------------------------
extern "C" void kernel_launch(void* const* d_in, const int* in_sizes, int n_in,
                              void* d_out, int out_size, void* d_ws, size_t ws_size,
                              hipStream_t stream) {
  // setup_inputs order: x, y, Wq, bq, Wk, bk, Wv, bv, Wo, bo
  const float* x  = (const float*)d_in[0];
  const float* y  = (const float*)d_in[1];
  const float* Wv = (const float*)d_in[6];
  const float* bv = (const float*)d_in[7];
  const float* Wo = (const float*)d_in[8];
  const float* bo = (const float*)d_in[9];
  float* z = (float*)d_out;

  // ws layout: ov (B*C*T floats = 7.86 MB) | WcT (256 KiB) | bc (1 KiB)
  float* ov  = (float*)d_ws;
  float* WcT = ov + (size_t)NROWS * T_DIM;
  float* bc  = WcT + C_DIM * C_DIM;

  make_wc<<<dim3(C_DIM), dim3(C_DIM), 0, stream>>>(Wo, Wv, bv, bo, WcT, bc);

  ov_kernel<<<dim3(B_DIM, C_DIM / CTILE), dim3(256), 0, stream>>>(y, WcT, bc, ov);

  add_kernel<<<dim3(ABLOCKS), dim3(ATHREADS), 0, stream>>>(x, ov, z);
}

// Round 8
// 97.785 us; speedup vs baseline: 1.2606x; 1.2606x over previous
//
#include <hip/hip_runtime.h>
#include <cstddef>

// Problem constants
#define B_DIM 64
#define C_DIM 256
#define T_DIM 120
#define V_DIM 25
#define TV    3000                      // T_DIM * V_DIM
#define CTILE 16
#define NROWS (B_DIM * C_DIM)           // 16384 rows of TV floats
#define ROWF4 (TV / 4)                  // 750 float4 per row

// add_kernel geometry: ATOTAL (f4 stride between batch elements) is an exact
// multiple of ROWF4, so each thread's within-row offset (t0, r, selects) is
// computed once and is loop-invariant.
// R8: 4x the blocks of R6 (6000 vs 1500) -> ~24000 waves, sustained ~full
// occupancy; BATCH=4, SUPERS=2 keeps zero remainder.
#define ABLOCKS 6000
#define ATHREADS 256
#define ATOTAL (ABLOCKS * ATHREADS)     // 1,536,000 f4 = 750 * 2048 rows
#define AROWSTEP (ATOTAL / ROWF4)       // 2048 rows per batch element
#define BATCH 4
#define SUPERS (NROWS / (AROWSTEP * BATCH))  // 2 exactly, zero remainder

typedef float f4v __attribute__((ext_vector_type(4)));

// ---------------------------------------------------------------------------
// Kernel A: fold the two linear layers.
//   WcT[i][c] = sum_j Wo[c][j] * Wv[j][i]
//   bc[c]     = sum_i Wo[c][i] * bv[i] + bo[c]
// ---------------------------------------------------------------------------
__global__ __launch_bounds__(256) void make_wc(
    const float* __restrict__ Wo, const float* __restrict__ Wv,
    const float* __restrict__ bv, const float* __restrict__ bo,
    float* __restrict__ WcT, float* __restrict__ bc) {
  const int c = blockIdx.x;
  const int i = threadIdx.x;

  float acc = 0.0f;
#pragma unroll 8
  for (int j = 0; j < C_DIM; ++j) {
    acc = fmaf(Wo[c * C_DIM + j], Wv[j * C_DIM + i], acc);
  }
  WcT[i * C_DIM + c] = acc;

  __shared__ float red[C_DIM];
  red[i] = Wo[c * C_DIM + i] * bv[i];
  __syncthreads();
  for (int s = 128; s > 0; s >>= 1) {
    if (i < s) red[i] += red[i + s];
    __syncthreads();
  }
  if (i == 0) bc[c] = red[0] + bo[c];
}

// ---------------------------------------------------------------------------
// Kernel B: ov[b*C + c][t] = bc[c] + sum_i WcT[i][c] * y[b][i][t]
// grid = (B, C/CTILE), block = 256. y loads double-buffered; WcT wave-uniform.
// ---------------------------------------------------------------------------
__global__ __launch_bounds__(256) void ov_kernel(
    const float* __restrict__ y, const float* __restrict__ WcT,
    const float* __restrict__ bc, float* __restrict__ ov) {
  const int b   = blockIdx.x;
  const int c0  = blockIdx.y * CTILE;
  const int tid = threadIdx.x;
  const int chalf = tid >> 7;      // wave-uniform
  const int t     = tid & 127;
  if (t >= T_DIM) return;

  const int cb = __builtin_amdgcn_readfirstlane(c0 + chalf * 8);

  float acc[8];
#pragma unroll
  for (int cl = 0; cl < 8; ++cl) acc[cl] = bc[cb + cl];

  const float* yb = y + (size_t)b * C_DIM * T_DIM + t;

  float yv[8];
#pragma unroll
  for (int u = 0; u < 8; ++u) yv[u] = yb[(size_t)u * T_DIM];

#define FMA_GROUP(ibase)                                              \
  _Pragma("unroll")                                                   \
  for (int u = 0; u < 8; ++u) {                                       \
    const f4v* wr = (const f4v*)(WcT + ((ibase) + u) * C_DIM + cb);   \
    const f4v w0 = wr[0];                                             \
    const f4v w1 = wr[1];                                             \
    acc[0] = fmaf(w0.x, yv[u], acc[0]);                               \
    acc[1] = fmaf(w0.y, yv[u], acc[1]);                               \
    acc[2] = fmaf(w0.z, yv[u], acc[2]);                               \
    acc[3] = fmaf(w0.w, yv[u], acc[3]);                               \
    acc[4] = fmaf(w1.x, yv[u], acc[4]);                               \
    acc[5] = fmaf(w1.y, yv[u], acc[5]);                               \
    acc[6] = fmaf(w1.z, yv[u], acc[6]);                               \
    acc[7] = fmaf(w1.w, yv[u], acc[7]);                               \
  }

  for (int i = 0; i < C_DIM - 8; i += 8) {
    float yn[8];
#pragma unroll
    for (int u = 0; u < 8; ++u) yn[u] = yb[(size_t)(i + 8 + u) * T_DIM];
    FMA_GROUP(i)
#pragma unroll
    for (int u = 0; u < 8; ++u) yv[u] = yn[u];
  }
  FMA_GROUP(C_DIM - 8)
#undef FMA_GROUP

  float* ovp = ov + ((size_t)b * C_DIM + cb) * T_DIM + t;
#pragma unroll
  for (int cl = 0; cl < 8; ++cl) ovp[(size_t)cl * T_DIM] = acc[cl];
}

// ---------------------------------------------------------------------------
// Kernel C: streaming z = x + ov[row][t0].
// nt stores (A/B-proven better than plain: R6 98.5 vs R7 123.3 total).
// R8 experiment: 4x waves (6000 blocks) + sched_barrier-pinned load cluster
// to test whether the ~2.3 TB/s nt-write rate scales with parallelism.
// ---------------------------------------------------------------------------
__global__ __launch_bounds__(ATHREADS) void add_kernel(
    const float* __restrict__ x, const float* __restrict__ ov,
    float* __restrict__ z) {
  const int gtid = blockIdx.x * ATHREADS + threadIdx.x;  // [0, ATOTAL)
  const int row0 = gtid / ROWF4;                         // [0, AROWSTEP)
  const int w4   = gtid - row0 * ROWF4;                  // [0, 750)
  const int pos  = w4 * 4;
  const int t0   = pos / V_DIM;
  const int r    = pos - t0 * V_DIM;                     // 0..24

  // component j uses next t's addend iff r + j >= 25; crossing implies
  // pos+3 < 3000 so t0+1 <= 119 (in bounds). If no cross, o1 = t0 (safe).
  const bool s1 = (r + 1 >= V_DIM), s2 = (r + 2 >= V_DIM), s3 = (r + 3 >= V_DIM);
  const int  o1 = t0 + (s3 ? 1 : 0);

  const f4v* __restrict__ xin  = (const f4v*)x;
  f4v* __restrict__       zout = (f4v*)z;

  size_t idx = (size_t)gtid;
  const float* ovp = ov + (size_t)row0 * T_DIM;

  for (int s = 0; s < SUPERS; ++s) {
    f4v   xv[BATCH];
    float a0[BATCH], a1[BATCH];

#pragma unroll
    for (int j = 0; j < BATCH; ++j)
      xv[j] = xin[idx + (size_t)j * ATOTAL];

#pragma unroll
    for (int j = 0; j < BATCH; ++j) {
      const float* o = ovp + (size_t)j * AROWSTEP * T_DIM;
      a0[j] = o[t0];
      a1[j] = o[o1];
    }

    // Pin: all 4 x-loads + 8 ov-loads issued before any add/store below.
    __builtin_amdgcn_sched_barrier(0);

#pragma unroll
    for (int j = 0; j < BATCH; ++j) {
      f4v o;
      o.x = xv[j].x + a0[j];
      o.y = xv[j].y + (s1 ? a1[j] : a0[j]);
      o.z = xv[j].z + (s2 ? a1[j] : a0[j]);
      o.w = xv[j].w + (s3 ? a1[j] : a0[j]);
      __builtin_nontemporal_store(o, &zout[idx + (size_t)j * ATOTAL]);
    }

    idx += (size_t)BATCH * ATOTAL;
    ovp += (size_t)BATCH * AROWSTEP * T_DIM;
  }
}

// ---------------------------------------------------------------------------
extern "C" void kernel_launch(void* const* d_in, const int* in_sizes, int n_in,
                              void* d_out, int out_size, void* d_ws, size_t ws_size,
                              hipStream_t stream) {
  // setup_inputs order: x, y, Wq, bq, Wk, bk, Wv, bv, Wo, bo
  const float* x  = (const float*)d_in[0];
  const float* y  = (const float*)d_in[1];
  const float* Wv = (const float*)d_in[6];
  const float* bv = (const float*)d_in[7];
  const float* Wo = (const float*)d_in[8];
  const float* bo = (const float*)d_in[9];
  float* z = (float*)d_out;

  // ws layout: ov (B*C*T floats = 7.86 MB) | WcT (256 KiB) | bc (1 KiB)
  float* ov  = (float*)d_ws;
  float* WcT = ov + (size_t)NROWS * T_DIM;
  float* bc  = WcT + C_DIM * C_DIM;

  make_wc<<<dim3(C_DIM), dim3(C_DIM), 0, stream>>>(Wo, Wv, bv, bo, WcT, bc);

  ov_kernel<<<dim3(B_DIM, C_DIM / CTILE), dim3(256), 0, stream>>>(y, WcT, bc, ov);

  add_kernel<<<dim3(ABLOCKS), dim3(ATHREADS), 0, stream>>>(x, ov, z);
}